// Round 9
// baseline (183.062 us; speedup 1.0000x reference)
//
#include <hip/hip_runtime.h>
#include <hip/hip_bf16.h>
#include <math.h>

#define N_NODES 50000
#define N_EDGES 800000
#define F 64
#define CUTOFF2 100.0f

#define NPB 50                 // nodes per bucket
#define NBUCKET 1000           // 50000 / 50 exactly
#define CAP 512                // records per bucket (mean ~225, sigma ~15)
#define NODE_BLOCKS 782        // ceil(3125 node-tiles / 4 waves-per-block)
#define PREP_BLOCKS 3125       // 800000 / 256 exactly
#define MAIN_BLOCKS 512        // persistent: exactly 2 blocks/CU on 256 CUs
#define MAIN_THREADS 512       // 8 waves per block

typedef __attribute__((ext_vector_type(8))) short bf16x8;   // 8 bf16 = 4 VGPR
typedef __attribute__((ext_vector_type(4))) float f32x4;    // MFMA C/D

__device__ __forceinline__ float silu_f(float v) {
    return v / (1.0f + __expf(-v));
}

// f32 -> bf16 bits, round-to-nearest-even
__device__ __forceinline__ unsigned short bf16_rne(float f) {
    unsigned int u = __float_as_uint(f);
    unsigned int r = (u + 0x7FFFu + ((u >> 16) & 1u)) >> 16;
    return (unsigned short)r;
}
__device__ __forceinline__ float bf16_f32(unsigned short h) {
    return __uint_as_float(((unsigned int)h) << 16);
}

// ---------------------------------------------------------------------------
// 16-row GEMM tile vs 64x64 row-major W (3-term bf16 split ~ f32 accuracy).
// MFMA f32_16x16x32_bf16 layouts (refcheck-verified rounds 3-8):
//   A: row = lane&15, k = (lane>>4)*8 + j
//   B: col = lane&15, k = (lane>>4)*8 + j
//   D: col = lane&15, row = (lane>>4)*4 + reg
// ---------------------------------------------------------------------------
__device__ __forceinline__ void gemm16_store(
    const bf16x8 (&Ah)[2], const bf16x8 (&Al)[2],
    const float* __restrict__ W, const float* __restrict__ bias,
    float* __restrict__ dst, int n0, int r, int g)
{
    #pragma unroll
    for (int c = 0; c < 4; ++c) {
        f32x4 acc = {0.f, 0.f, 0.f, 0.f};
        #pragma unroll
        for (int t = 0; t < 2; ++t) {
            bf16x8 bh, bl;
            #pragma unroll
            for (int j = 0; j < 8; ++j) {
                const float wv = W[(size_t)(t * 32 + g * 8 + j) * F + c * 16 + r];
                const unsigned short hb = bf16_rne(wv);
                bh[j] = (short)hb;
                bl[j] = (short)bf16_rne(wv - bf16_f32(hb));
            }
            acc = __builtin_amdgcn_mfma_f32_16x16x32_bf16(Ah[t], bh, acc, 0, 0, 0);
            acc = __builtin_amdgcn_mfma_f32_16x16x32_bf16(Al[t], bh, acc, 0, 0, 0);
            acc = __builtin_amdgcn_mfma_f32_16x16x32_bf16(Ah[t], bl, acc, 0, 0, 0);
        }
        const float bb = bias[c * 16 + r];
        #pragma unroll
        for (int rg = 0; rg < 4; ++rg) {
            dst[(size_t)(n0 + g * 4 + rg) * F + c * 16 + r] = acc[rg] + bb;
        }
    }
}

// ---------------------------------------------------------------------------
// Kernel 1 (fused): blocks [0, NODE_BLOCKS) do node projections via MFMA;
// blocks [NODE_BLOCKS, ...) do edge prep: cutoff test + radial MLP +
// scatter into per-target-bucket regions.  (unchanged from R8)
// Record (32B): {src, tgt, r0, r1, r2, r3, cutoff, pad}.
// ---------------------------------------------------------------------------
__global__ __launch_bounds__(256) void node_prep_kernel(
    const float* __restrict__ x, const float* __restrict__ Wp,
    const float* __restrict__ bp, const float* __restrict__ W1,
    const float* __restrict__ b1,
    const int* __restrict__ ei, const float* __restrict__ pos,
    const float* __restrict__ Wr1, const float* __restrict__ br1,
    const float* __restrict__ Wr2, const float* __restrict__ br2,
    float* __restrict__ out, float* __restrict__ h1,
    float* __restrict__ recs, int* __restrict__ counts)
{
    if (blockIdx.x < NODE_BLOCKS) {
        const int lane = threadIdx.x & 63;
        const int gw   = blockIdx.x * 4 + (threadIdx.x >> 6);
        if (gw >= N_NODES / 16) return;
        const int n0 = gw * 16;
        const int r = lane & 15, g = lane >> 4;

        bf16x8 Ah[2], Al[2];
        #pragma unroll
        for (int t = 0; t < 2; ++t) {
            const float* xp = x + (size_t)(n0 + r) * F + t * 32 + g * 8;
            #pragma unroll
            for (int j = 0; j < 8; ++j) {
                const float v = xp[j];
                const unsigned short hb = bf16_rne(v);
                Ah[t][j] = (short)hb;
                Al[t][j] = (short)bf16_rne(v - bf16_f32(hb));
            }
        }
        gemm16_store(Ah, Al, Wp, bp, out, n0, r, g);
        gemm16_store(Ah, Al, W1, b1, h1, n0, r, g);
    } else {
        const int e = (blockIdx.x - NODE_BLOCKS) * 256 + threadIdx.x;
        if (e >= N_EDGES) return;
        const int src = ei[e];
        const int tgt = ei[N_EDGES + e];
        const float dx = pos[3 * tgt + 0] - pos[3 * src + 0];
        const float dy = pos[3 * tgt + 1] - pos[3 * src + 1];
        const float dz = pos[3 * tgt + 2] - pos[3 * src + 2];
        const float d2 = dx * dx + dy * dy + dz * dz;
        if (d2 >= CUTOFF2) return;

        const float d = sqrtf(d2);
        float a0 = br2[0], a1 = br2[1], a2 = br2[2], a3 = br2[3];
        #pragma unroll
        for (int i = 0; i < 16; ++i) {
            const float t = silu_f(fmaf(d, Wr1[i], br1[i]));
            a0 = fmaf(t, Wr2[i * 4 + 0], a0);
            a1 = fmaf(t, Wr2[i * 4 + 1], a1);
            a2 = fmaf(t, Wr2[i * 4 + 2], a2);
            a3 = fmaf(t, Wr2[i * 4 + 3], a3);
        }
        const float r0 = silu_f(a0), r1 = silu_f(a1);
        const float r2 = silu_f(a2), r3 = silu_f(a3);
        const float cut = 1.0f - d2 * 0.01f;    // in (0,1] when d2 < 100

        const int b   = tgt / NPB;
        const int idx = atomicAdd(&counts[b], 1);
        if (idx < CAP) {
            float4* p = (float4*)(recs + ((size_t)b * CAP + idx) * 8);
            p[0] = make_float4(__int_as_float(src), __int_as_float(tgt), r0, r1);
            p[1] = make_float4(r2, r3, cut, 0.0f);
        }
    }
}

// ---------------------------------------------------------------------------
// Kernel 2 (R9): PERSISTENT blocks. 512 blocks x 512 threads (8 waves) =
// exactly 2 blocks/CU resident for the whole kernel. Each block loops over
// buckets (blk += gridDim.x), fills sB/sW1 ONCE, zeroes/flushes agg per
// bucket. Tile body is byte-identical to the refcheck-verified R7 body.
// Evidence driving this: R4-R8 all show OccupancyPercent 17-24% (~1.3-2
// waves/SIMD average) with no resource cap -> block-batch serialization +
// 1000x prologue refill was the suspected stall; this removes both.
// ---------------------------------------------------------------------------
__global__ __launch_bounds__(MAIN_THREADS) void edge_main_kernel(
    const float* __restrict__ recs, const int* __restrict__ counts,
    const float* __restrict__ h1, const float* __restrict__ W1,
    const float* __restrict__ W2, const float* __restrict__ b2,
    float* __restrict__ out)
{
    __shared__ __align__(16) float agg[NPB][F + 1];   // 13000 B, +1 pad
    __shared__ __align__(16) short sB[4][2][64][8];   // 4096 B
    __shared__ __align__(16) float sW1[4][2][4][8];   // 1024 B

    const int tid  = threadIdx.x;
    const int lane = tid & 63;
    const int w    = tid >> 6;            // 0..7
    const int r    = lane & 15, g = lane >> 4;

    // ---- one-time prologue: weights into LDS ----
    if (tid < 256) {
        // sB: W2[k][n] -> sB[n>>4][k>>5][((k>>3)&3)*16 + (n&15)][k&7]
        #pragma unroll
        for (int q = 0; q < 4; ++q) {
            const int f = tid * 16 + q * 4;
            float tmp[4];
            *(float4*)tmp = *(const float4*)&W2[f];
            #pragma unroll
            for (int m = 0; m < 4; ++m) {
                const int ff = f + m;
                const int k = ff >> 6, n = ff & 63;
                sB[n >> 4][k >> 5][(((k >> 3) & 3) << 4) | (n & 15)][k & 7] =
                    (short)bf16_rne(tmp[m]);
            }
        }
    } else {
        // sW1: threads 256..511 cover 4*64 values exactly.
        const int t2 = tid - 256;
        const int i = t2 >> 6, k = t2 & 63;
        sW1[i][k >> 5][(k >> 3) & 3][k & 7] = W1[(size_t)(F + i) * F + k];
    }

    float b2c[4];
    #pragma unroll
    for (int c = 0; c < 4; ++c) b2c[c] = b2[c * 16 + r];

    // ---- persistent bucket loop ----
    for (int blk = blockIdx.x; blk < NBUCKET; blk += gridDim.x) {
        const int cnt = min(counts[blk], CAP);
        if (cnt == 0) continue;          // block-uniform

        // zero agg; barrier also orders the one-time weight fill (1st iter)
        for (int i = tid; i < NPB * (F + 1); i += MAIN_THREADS)
            agg[i / (F + 1)][i % (F + 1)] = 0.f;
        __syncthreads();

        const int node0 = blk * NPB;
        const float* rbase = recs + (size_t)blk * CAP * 8;
        const int ntiles = (cnt + 15) >> 4;

        for (int s = w; s < ntiles; s += 8) {
            const int base = s << 4;
            // Branch-free record load: all 64 lanes load edge (base + r).
            const int er = min(base + r, cnt - 1);
            const float4 ra = *(const float4*)(rbase + (size_t)er * 8);
            const float4 rb = *(const float4*)(rbase + (size_t)er * 8 + 4);

            // Epilogue metadata (per-g quarter owns 4 rows of the D tile).
            int   lrow_e[4]; float cut_e[4];
            #pragma unroll
            for (int rg = 0; rg < 4; ++rg) {
                lrow_e[rg] = __shfl(__float_as_int(ra.y), g * 4 + rg) - node0;
                cut_e[rg]  = __shfl(rb.z, g * 4 + rg);
            }

            // Gather h1[src] directly in A-fragment layout.
            const int src = __float_as_int(ra.x);
            const float* hp = h1 + (size_t)src * F + g * 8;
            const float4 q00 = *(const float4*)(hp);
            const float4 q01 = *(const float4*)(hp + 4);
            const float4 q10 = *(const float4*)(hp + 32);
            const float4 q11 = *(const float4*)(hp + 36);

            float hv[2][8];
            hv[0][0] = q00.x; hv[0][1] = q00.y; hv[0][2] = q00.z; hv[0][3] = q00.w;
            hv[0][4] = q01.x; hv[0][5] = q01.y; hv[0][6] = q01.z; hv[0][7] = q01.w;
            hv[1][0] = q10.x; hv[1][1] = q10.y; hv[1][2] = q10.z; hv[1][3] = q10.w;
            hv[1][4] = q11.x; hv[1][5] = q11.y; hv[1][6] = q11.z; hv[1][7] = q11.w;

            // Rank-4 radial update + silu, then cvt to bf16 A-fragments.
            bf16x8 ah[2];
            #pragma unroll
            for (int t = 0; t < 2; ++t) {
                float w0[8], w1a[8], w2a[8], w3a[8];
                *(float4*)&w0[0]  = *(const float4*)&sW1[0][t][g][0];
                *(float4*)&w0[4]  = *(const float4*)&sW1[0][t][g][4];
                *(float4*)&w1a[0] = *(const float4*)&sW1[1][t][g][0];
                *(float4*)&w1a[4] = *(const float4*)&sW1[1][t][g][4];
                *(float4*)&w2a[0] = *(const float4*)&sW1[2][t][g][0];
                *(float4*)&w2a[4] = *(const float4*)&sW1[2][t][g][4];
                *(float4*)&w3a[0] = *(const float4*)&sW1[3][t][g][0];
                *(float4*)&w3a[4] = *(const float4*)&sW1[3][t][g][4];
                #pragma unroll
                for (int j = 0; j < 8; ++j) {
                    float h = hv[t][j];
                    h = fmaf(ra.z, w0[j],  h);
                    h = fmaf(ra.w, w1a[j], h);
                    h = fmaf(rb.x, w2a[j], h);
                    h = fmaf(rb.y, w3a[j], h);
                    ah[t][j] = (short)bf16_rne(silu_f(h));
                }
            }

            // [16 x 64] @ W2 via 8 MFMAs; B-fragment = 1 ds_read_b128 each.
            f32x4 acc[4] = {};
            #pragma unroll
            for (int t = 0; t < 2; ++t)
                #pragma unroll
                for (int c = 0; c < 4; ++c) {
                    const bf16x8 bb = *(const bf16x8*)&sB[c][t][lane][0];
                    acc[c] = __builtin_amdgcn_mfma_f32_16x16x32_bf16(
                        ah[t], bb, acc[c], 0, 0, 0);
                }

            // Epilogue: bias + silu + cutoff -> ds_add_f32.
            #pragma unroll
            for (int rg = 0; rg < 4; ++rg) {
                if (base + g * 4 + rg < cnt) {
                    #pragma unroll
                    for (int c = 0; c < 4; ++c) {
                        const float v = silu_f(acc[c][rg] + b2c[c]) * cut_e[rg];
                        unsafeAtomicAdd(&agg[lrow_e[rg]][c * 16 + r], v);
                    }
                }
            }
        }

        __syncthreads();
        // Flush: bucket rows are exclusive to this block -> plain +=.
        for (int i = tid; i < NPB * F; i += MAIN_THREADS) {
            out[(size_t)(node0 + (i >> 6)) * F + (i & 63)] += agg[i >> 6][i & 63];
        }
        __syncthreads();   // flush reads done before next bucket's zero
    }
}

extern "C" void kernel_launch(void* const* d_in, const int* in_sizes, int n_in,
                              void* d_out, int out_size, void* d_ws, size_t ws_size,
                              hipStream_t stream) {
    const float* x   = (const float*)d_in[0];
    const int*   ei  = (const int*)d_in[1];
    const float* pos = (const float*)d_in[2];
    const float* Wp  = (const float*)d_in[3];
    const float* bp  = (const float*)d_in[4];
    const float* W1  = (const float*)d_in[5];
    const float* b1  = (const float*)d_in[6];
    const float* W2  = (const float*)d_in[7];
    const float* b2  = (const float*)d_in[8];
    const float* Wr1 = (const float*)d_in[9];
    const float* br1 = (const float*)d_in[10];
    const float* Wr2 = (const float*)d_in[11];
    const float* br2 = (const float*)d_in[12];
    float* out = (float*)d_out;

    // workspace: [counts 8KB][h1 12.8MB][recs 1000*512*32B = 16.4MB]
    char*  ws     = (char*)d_ws;
    int*   counts = (int*)ws;
    float* h1     = (float*)(ws + 8192);
    float* recs   = (float*)(ws + 8192 + (size_t)N_NODES * F * sizeof(float));

    hipMemsetAsync(counts, 0, NBUCKET * sizeof(int), stream);
    node_prep_kernel<<<NODE_BLOCKS + PREP_BLOCKS, 256, 0, stream>>>(
        x, Wp, bp, W1, b1, ei, pos, Wr1, br1, Wr2, br2,
        out, h1, recs, counts);
    edge_main_kernel<<<MAIN_BLOCKS, MAIN_THREADS, 0, stream>>>(
        recs, counts, h1, W1, W2, b2, out);
}

// Round 10
// 86.973 us; speedup vs baseline: 2.1048x; 2.1048x over previous
//
#include <hip/hip_runtime.h>
#include <hip/hip_bf16.h>
#include <math.h>

#define N_NODES 50000
#define N_EDGES 800000
#define F 64
#define CUTOFF2 100.0f
#define P_BLOCKS 2048
#define CHUNK 391            // ceil(800000 / 2048)

typedef __attribute__((ext_vector_type(8))) short bf16x8;   // 8 bf16 = 4 VGPR
typedef __attribute__((ext_vector_type(4))) float f32x4;    // MFMA C/D

// Division-free silu: v * rcp(1 + exp2(-v*log2e)).
// R10 FIX: plain "v / (1+expf(-v))" compiled to the full IEEE divide
// (div_scale + rcp + 3 fma + div_fmas + div_fixup ~ 13 ops, 2 TRANS).
// With 32 silus/tile (main) and 20 silus/edge (prep) that was ~4x the
// kernel's static instruction count (VALUBusy-derived: 1200 wave-inst/tile
// vs ~300 expected). rcp approx is ~1 ulp; limits exact (rcp(inf)=0).
__device__ __forceinline__ float silu_f(float v) {
    return v * __builtin_amdgcn_rcpf(1.0f + __expf(-v));
}

// f32 -> bf16 bits, round-to-nearest-even
__device__ __forceinline__ unsigned short bf16_rne(float f) {
    unsigned int u = __float_as_uint(f);
    unsigned int r = (u + 0x7FFFu + ((u >> 16) & 1u)) >> 16;
    return (unsigned short)r;
}
__device__ __forceinline__ float bf16_f32(unsigned short h) {
    return __uint_as_float(((unsigned int)h) << 16);
}

// ---------------------------------------------------------------------------
// Kernel 1: node projections via MFMA (3-term bf16 split, near-f32 accuracy).
//   out[n] = x[n] @ Wp + bp ; h1[n] = x[n] @ W1[:64] + b1
// One wave per 16-node tile (50000 = 3125 * 16 exactly).
// MFMA f32_16x16x32_bf16 layouts (refcheck-verified rounds 3-9):
//   A: row = lane&15, k = (lane>>4)*8 + j
//   B: col = lane&15, k = (lane>>4)*8 + j
//   D: col = lane&15, row = (lane>>4)*4 + reg
// ---------------------------------------------------------------------------
__device__ __forceinline__ void gemm16_store(
    const bf16x8 (&Ah)[2], const bf16x8 (&Al)[2],
    const float* __restrict__ W, const float* __restrict__ bias,
    float* __restrict__ dst, int n0, int r, int g)
{
    #pragma unroll
    for (int c = 0; c < 4; ++c) {
        f32x4 acc = {0.f, 0.f, 0.f, 0.f};
        #pragma unroll
        for (int t = 0; t < 2; ++t) {
            bf16x8 bh, bl;
            #pragma unroll
            for (int j = 0; j < 8; ++j) {
                const float wv = W[(size_t)(t * 32 + g * 8 + j) * F + c * 16 + r];
                const unsigned short hb = bf16_rne(wv);
                bh[j] = (short)hb;
                bl[j] = (short)bf16_rne(wv - bf16_f32(hb));
            }
            acc = __builtin_amdgcn_mfma_f32_16x16x32_bf16(Ah[t], bh, acc, 0, 0, 0);
            acc = __builtin_amdgcn_mfma_f32_16x16x32_bf16(Al[t], bh, acc, 0, 0, 0);
            acc = __builtin_amdgcn_mfma_f32_16x16x32_bf16(Ah[t], bl, acc, 0, 0, 0);
        }
        const float bb = bias[c * 16 + r];
        #pragma unroll
        for (int rg = 0; rg < 4; ++rg) {
            dst[(size_t)(n0 + g * 4 + rg) * F + c * 16 + r] = acc[rg] + bb;
        }
    }
}

__global__ __launch_bounds__(256) void node_kernel(
    const float* __restrict__ x, const float* __restrict__ Wp,
    const float* __restrict__ bp, const float* __restrict__ W1,
    const float* __restrict__ b1, float* __restrict__ out,
    float* __restrict__ h1)
{
    const int lane = threadIdx.x & 63;
    const int gw   = blockIdx.x * 4 + (threadIdx.x >> 6);
    if (gw >= N_NODES / 16) return;
    const int n0 = gw * 16;
    const int r = lane & 15, g = lane >> 4;

    bf16x8 Ah[2], Al[2];
    #pragma unroll
    for (int t = 0; t < 2; ++t) {
        const float* xp = x + (size_t)(n0 + r) * F + t * 32 + g * 8;
        #pragma unroll
        for (int j = 0; j < 8; ++j) {
            const float v = xp[j];
            const unsigned short hb = bf16_rne(v);
            Ah[t][j] = (short)hb;
            Al[t][j] = (short)bf16_rne(v - bf16_f32(hb));
        }
    }
    gemm16_store(Ah, Al, Wp, bp, out, n0, r, g);
    gemm16_store(Ah, Al, W1, b1, h1, n0, r, g);
}

// ---------------------------------------------------------------------------
// Kernel 2: cutoff test + radial MLP + per-block-region compaction.
// Record (32B): {src, tgt, r0, r1, r2, r3, cutoff, pad}. LDS counter only.
// ---------------------------------------------------------------------------
__global__ __launch_bounds__(256) void edge_prep_kernel(
    const int* __restrict__ ei, const float* __restrict__ pos,
    const float* __restrict__ Wr1, const float* __restrict__ br1,
    const float* __restrict__ Wr2, const float* __restrict__ br2,
    float* __restrict__ recs, int* __restrict__ counts)
{
    __shared__ int s_off;
    if (threadIdx.x == 0) s_off = 0;
    __syncthreads();

    const int lane = threadIdx.x & 63;
    const int j    = blockIdx.x;
    const int e0   = j * CHUNK;
    const int e1   = min(e0 + CHUNK, N_EDGES);
    float* rbase   = recs + (size_t)j * CHUNK * 8;

    for (int base = e0; base < e1; base += 256) {
        const int e = base + threadIdx.x;
        bool  active = false;
        float r0 = 0.f, r1 = 0.f, r2 = 0.f, r3 = 0.f, cut = 0.f;
        int   src = 0, tgt = 0;

        if (e < e1) {
            src = ei[e];
            tgt = ei[N_EDGES + e];
            const float dx = pos[3 * tgt + 0] - pos[3 * src + 0];
            const float dy = pos[3 * tgt + 1] - pos[3 * src + 1];
            const float dz = pos[3 * tgt + 2] - pos[3 * src + 2];
            const float d2 = dx * dx + dy * dy + dz * dz;
            if (d2 < CUTOFF2) {
                active = true;
                const float d = sqrtf(d2);
                float a0 = br2[0], a1 = br2[1], a2 = br2[2], a3 = br2[3];
                #pragma unroll
                for (int i = 0; i < 16; ++i) {
                    const float t = silu_f(fmaf(d, Wr1[i], br1[i]));
                    a0 = fmaf(t, Wr2[i * 4 + 0], a0);
                    a1 = fmaf(t, Wr2[i * 4 + 1], a1);
                    a2 = fmaf(t, Wr2[i * 4 + 2], a2);
                    a3 = fmaf(t, Wr2[i * 4 + 3], a3);
                }
                r0 = silu_f(a0); r1 = silu_f(a1);
                r2 = silu_f(a2); r3 = silu_f(a3);
                cut = 1.0f - d2 * 0.01f;   // in (0,1] when d2 < 100
            }
        }

        const unsigned long long m = __ballot(active);
        const int cntw = __popcll(m);
        int wbase = 0;
        if (lane == 0 && cntw) wbase = atomicAdd(&s_off, cntw);   // LDS atomic
        wbase = __shfl(wbase, 0);
        if (active) {
            const int idx = wbase + __popcll(m & ((1ull << lane) - 1ull));
            float4* p = (float4*)(rbase + (size_t)idx * 8);
            p[0] = make_float4(__int_as_float(src), __int_as_float(tgt), r0, r1);
            p[1] = make_float4(r2, r3, cut, 0.0f);
        }
    }

    __syncthreads();
    if (threadIdx.x == 0) counts[j] = s_off;
}

// ---------------------------------------------------------------------------
// Kernel 3: edge MLP via MFMA, NO LDS, NO branches in the tile body.
// (R4 structure verbatim — best measured config — with fast silu.)
// Per 16-edge tile, lane (r,g):
//   - loads edge (base+r)'s 32B record (index clamped; 4x g-redundant)
//   - gathers h1[src][t*32+g*8..+7] directly in MFMA-A layout (4 dwordx4)
//   - rank-4 radial update + silu lane-locally, cvt to bf16 A-fragment
//   - 8 MFMAs vs W2 bf16 fragments held in VGPRs
//   - tgt/cut for epilogue via __shfl; predicated coalesced atomics
// ---------------------------------------------------------------------------
__global__ __launch_bounds__(256, 3) void edge_main_kernel(
    const float* __restrict__ recs, const int* __restrict__ counts,
    const float* __restrict__ h1, const float* __restrict__ W1,
    const float* __restrict__ W2, const float* __restrict__ b2,
    float* __restrict__ out)
{
    const int lane = threadIdx.x & 63;
    const int w    = threadIdx.x >> 6;
    const int blk  = blockIdx.x;
    const int r    = lane & 15, g = lane >> 4;

    // W2 B-fragments, bf16 single term (32 VGPRs).
    bf16x8 Bh[4][2];
    #pragma unroll
    for (int c = 0; c < 4; ++c)
        #pragma unroll
        for (int t = 0; t < 2; ++t)
            #pragma unroll
            for (int jj = 0; jj < 8; ++jj)
                Bh[c][t][jj] = (short)bf16_rne(
                    W2[(size_t)(t * 32 + g * 8 + jj) * F + c * 16 + r]);

    // W1 radial rows 64..67, this lane's k-slice (64 VGPRs, f32).
    float w1r[4][2][8];
    #pragma unroll
    for (int i = 0; i < 4; ++i)
        #pragma unroll
        for (int t = 0; t < 2; ++t) {
            const float4 wa = *(const float4*)&W1[(size_t)(F + i) * F + t * 32 + g * 8];
            const float4 wb = *(const float4*)&W1[(size_t)(F + i) * F + t * 32 + g * 8 + 4];
            w1r[i][t][0] = wa.x; w1r[i][t][1] = wa.y;
            w1r[i][t][2] = wa.z; w1r[i][t][3] = wa.w;
            w1r[i][t][4] = wb.x; w1r[i][t][5] = wb.y;
            w1r[i][t][6] = wb.z; w1r[i][t][7] = wb.w;
        }

    float b2c[4];
    #pragma unroll
    for (int c = 0; c < 4; ++c) b2c[c] = b2[c * 16 + r];

    const int cnt = counts[blk];
    const float* rbase = recs + (size_t)blk * CHUNK * 8;
    const int ntiles = (cnt + 15) >> 4;

    for (int s = w; s < ntiles; s += 4) {
        const int base = s << 4;
        // Branch-free record load: all 64 lanes load edge (base + r).
        const int er = min(base + r, cnt - 1);
        const float4 ra = *(const float4*)(rbase + (size_t)er * 8);
        const float4 rb = *(const float4*)(rbase + (size_t)er * 8 + 4);

        // Epilogue metadata early.
        int   tgt_e[4]; float cut_e[4];
        #pragma unroll
        for (int rg = 0; rg < 4; ++rg) {
            tgt_e[rg] = __shfl(__float_as_int(ra.y), g * 4 + rg);
            cut_e[rg] = __shfl(rb.z, g * 4 + rg);
        }

        // Gather h1[src] directly in A-fragment layout (4 independent dwordx4).
        const int src = __float_as_int(ra.x);
        const float* hp = h1 + (size_t)src * F + g * 8;
        const float4 q00 = *(const float4*)(hp);
        const float4 q01 = *(const float4*)(hp + 4);
        const float4 q10 = *(const float4*)(hp + 32);
        const float4 q11 = *(const float4*)(hp + 36);

        float hv[2][8];
        hv[0][0] = q00.x; hv[0][1] = q00.y; hv[0][2] = q00.z; hv[0][3] = q00.w;
        hv[0][4] = q01.x; hv[0][5] = q01.y; hv[0][6] = q01.z; hv[0][7] = q01.w;
        hv[1][0] = q10.x; hv[1][1] = q10.y; hv[1][2] = q10.z; hv[1][3] = q10.w;
        hv[1][4] = q11.x; hv[1][5] = q11.y; hv[1][6] = q11.z; hv[1][7] = q11.w;

        // Rank-4 radial update + silu, then cvt to bf16 A-fragments.
        bf16x8 ah[2];
        #pragma unroll
        for (int t = 0; t < 2; ++t)
            #pragma unroll
            for (int j = 0; j < 8; ++j) {
                float h = hv[t][j];
                h = fmaf(ra.z, w1r[0][t][j], h);
                h = fmaf(ra.w, w1r[1][t][j], h);
                h = fmaf(rb.x, w1r[2][t][j], h);
                h = fmaf(rb.y, w1r[3][t][j], h);
                ah[t][j] = (short)bf16_rne(silu_f(h));
            }

        // [16 x 64] @ W2 via 8 MFMAs.
        f32x4 acc[4] = {};
        #pragma unroll
        for (int t = 0; t < 2; ++t)
            #pragma unroll
            for (int c = 0; c < 4; ++c)
                acc[c] = __builtin_amdgcn_mfma_f32_16x16x32_bf16(
                    ah[t], Bh[c][t], acc[c], 0, 0, 0);

        // Epilogue: bias + silu + cutoff, predicated coalesced atomics.
        #pragma unroll
        for (int rg = 0; rg < 4; ++rg) {
            if (base + g * 4 + rg < cnt) {
                #pragma unroll
                for (int c = 0; c < 4; ++c) {
                    const float v  = acc[c][rg] + b2c[c];
                    const float ef = silu_f(v) * cut_e[rg];
                    unsafeAtomicAdd(&out[(size_t)tgt_e[rg] * F + c * 16 + r], ef);
                }
            }
        }
    }
}

extern "C" void kernel_launch(void* const* d_in, const int* in_sizes, int n_in,
                              void* d_out, int out_size, void* d_ws, size_t ws_size,
                              hipStream_t stream) {
    const float* x   = (const float*)d_in[0];
    const int*   ei  = (const int*)d_in[1];
    const float* pos = (const float*)d_in[2];
    const float* Wp  = (const float*)d_in[3];
    const float* bp  = (const float*)d_in[4];
    const float* W1  = (const float*)d_in[5];
    const float* b1  = (const float*)d_in[6];
    const float* W2  = (const float*)d_in[7];
    const float* b2  = (const float*)d_in[8];
    const float* Wr1 = (const float*)d_in[9];
    const float* br1 = (const float*)d_in[10];
    const float* Wr2 = (const float*)d_in[11];
    const float* br2 = (const float*)d_in[12];
    float* out = (float*)d_out;

    // workspace layout: [counts 8KB][h1 12.8MB][recs 25.6MB]
    char*  ws     = (char*)d_ws;
    int*   counts = (int*)ws;
    float* h1     = (float*)(ws + P_BLOCKS * sizeof(int));
    float* recs   = (float*)(ws + P_BLOCKS * sizeof(int)
                             + (size_t)N_NODES * F * sizeof(float));

    node_kernel<<<(N_NODES / 16 + 3) / 4, 256, 0, stream>>>(
        x, Wp, bp, W1, b1, out, h1);
    edge_prep_kernel<<<P_BLOCKS, 256, 0, stream>>>(
        ei, pos, Wr1, br1, Wr2, br2, recs, counts);
    edge_main_kernel<<<P_BLOCKS, 256, 0, stream>>>(
        recs, counts, h1, W1, W2, b2, out);
}